// Round 1
// baseline (96.891 us; speedup 1.0000x reference)
//
#include <hip/hip_runtime.h>

#define H 1536
#define HK 8
#define HV 16
#define DK 64
#define DV 64
#define KEY_DIM 512
#define VALUE_DIM 1024
#define CONV_DIM 2048
#define NROWS1 (CONV_DIM + VALUE_DIM + HV + HV)   // 3104

__device__ __forceinline__ float wave_reduce_sum(float v) {
#pragma unroll
    for (int off = 32; off > 0; off >>= 1) v += __shfl_xor(v, off, 64);
    return v;
}

// Kernel 1: fused GEMV for W_qkv (2048), W_z (1024), W_a (16), W_b (16) vs x[1536].
// One 64-lane wave per row; 6 float4 loads per lane.
__global__ __launch_bounds__(256) void gemv_in(
        const float* __restrict__ x,
        const float* __restrict__ Wqkv, const float* __restrict__ Wz,
        const float* __restrict__ Wa,   const float* __restrict__ Wb,
        float* __restrict__ ws) {
    const int wave = threadIdx.x >> 6;
    const int lane = threadIdx.x & 63;
    const int row  = blockIdx.x * 4 + wave;          // 776 blocks * 4 = 3104
    const float* wrow;
    if (row < CONV_DIM)                      wrow = Wqkv + (size_t)row * H;
    else if (row < CONV_DIM + VALUE_DIM)     wrow = Wz + (size_t)(row - CONV_DIM) * H;
    else if (row < CONV_DIM + VALUE_DIM + HV)wrow = Wa + (size_t)(row - CONV_DIM - VALUE_DIM) * H;
    else                                     wrow = Wb + (size_t)(row - CONV_DIM - VALUE_DIM - HV) * H;
    const float4* w4 = (const float4*)wrow;
    const float4* x4 = (const float4*)x;
    float acc = 0.f;
#pragma unroll
    for (int j = 0; j < 6; ++j) {                    // 1536/4/64 = 6
        float4 a = w4[lane + 64 * j];
        float4 b = x4[lane + 64 * j];
        acc += a.x * b.x + a.y * b.y + a.z * b.z + a.w * b.w;
    }
    acc = wave_reduce_sum(acc);
    if (lane == 0) ws[row] = acc;
}

// Kernel 2: conv + silu + l2norm + delta rule + gated RMSNorm. One block per head.
__global__ __launch_bounds__(256) void decode_core(
        const float* __restrict__ ws,                 // [qkv 2048 | z 1024 | a 16 | b 16]
        const float* __restrict__ conv_w,             // [2048,4]
        const float* __restrict__ conv_cache,         // [2048,3]
        const float* __restrict__ A_log, const float* __restrict__ dt_bias,
        const float* __restrict__ norm_w,             // [64]
        const float* __restrict__ state,              // [16,64,64]
        float* __restrict__ out_gated) {              // [1024]
    const int h    = blockIdx.x;
    const int tid  = threadIdx.x;
    const int lane = tid & 63;
    const int grp  = tid >> 6;

    __shared__ float q_s[64], k_s[64], v_s[64];
    __shared__ float red_r[256], red_o[256];
    __shared__ float scal[3];                         // decay, beta, k·q

    // Phase A: conv + activation for the q/k/v rows this head needs.
    if (grp < 3) {
        int i;
        if (grp == 0)      i = (h >> 1) * 64 + lane;                // q row (kv-group repeat)
        else if (grp == 1) i = KEY_DIM + (h >> 1) * 64 + lane;      // k row
        else               i = 2 * KEY_DIM + h * 64 + lane;         // v row
        float raw = conv_cache[i * 3 + 0] * conv_w[i * 4 + 0]
                  + conv_cache[i * 3 + 1] * conv_w[i * 4 + 1]
                  + conv_cache[i * 3 + 2] * conv_w[i * 4 + 2]
                  + ws[i]                 * conv_w[i * 4 + 3];
        float c = raw / (1.f + expf(-raw));           // silu
        if (grp == 2) {
            v_s[lane] = c;
        } else {
            float ss  = wave_reduce_sum(c * c);
            float inv = rsqrtf(ss + 1e-12f);          // l2_normalize
            if (grp == 0) q_s[lane] = c * inv * 0.125f;  // * Dk^-0.5
            else          k_s[lane] = c * inv;
        }
    } else if (lane == 0) {
        float aa = ws[CONV_DIM + VALUE_DIM + h] + dt_bias[h];
        float sp = (aa > 20.f) ? aa : log1pf(expf(aa));  // softplus
        scal[0] = expf(-expf(A_log[h]) * sp);            // decay = exp(g)
        float braw = ws[CONV_DIM + VALUE_DIM + HV + h];
        scal[1] = 1.f / (1.f + expf(-braw));             // beta
    }
    __syncthreads();

    // Phase B: partial dots over the K dimension (each quarter covers 16 k's).
    const float* st = state + (size_t)h * DK * DV;
    float pr = 0.f, po = 0.f;
    const int k0 = grp * 16;
#pragma unroll
    for (int kk = 0; kk < 16; ++kk) {
        float s = st[(k0 + kk) * 64 + lane];          // coalesced over v
        pr += s * k_s[k0 + kk];
        po += s * q_s[k0 + kk];
    }
    red_r[tid] = pr;
    red_o[tid] = po;
    if (grp == 0) {                                   // k·q scalar
        float t = wave_reduce_sum(k_s[lane] * q_s[lane]);
        if (lane == 0) scal[2] = t;
    }
    __syncthreads();

    // Phase C: combine, delta rule, gated RMSNorm.
    if (tid < 64) {
        const float decay = scal[0], beta = scal[1], kq = scal[2];
        float r = (red_r[tid] + red_r[64 + tid] + red_r[128 + tid] + red_r[192 + tid]) * decay;
        float o = (red_o[tid] + red_o[64 + tid] + red_o[128 + tid] + red_o[192 + tid]) * decay;
        float delta = (v_s[tid] - r) * beta;
        float outv  = o + delta * kq;                 // new_state^T q without materializing it
        float ss  = wave_reduce_sum(outv * outv);
        float inv = rsqrtf(ss * (1.f / 64.f) + 1e-6f);
        float zz  = ws[CONV_DIM + h * 64 + tid];
        float gate = zz / (1.f + expf(-zz));          // silu(z)
        out_gated[h * 64 + tid] = norm_w[tid] * outv * inv * gate;
    }
}

// Kernel 3: y = W_out[1536,1024] @ out_gated. One wave per row, 4 float4 per lane.
__global__ __launch_bounds__(256) void gemv_out(
        const float* __restrict__ Wout, const float* __restrict__ og,
        float* __restrict__ y) {
    const int wave = threadIdx.x >> 6;
    const int lane = threadIdx.x & 63;
    const int row  = blockIdx.x * 4 + wave;           // 384 blocks * 4 = 1536
    const float4* w4 = (const float4*)(Wout + (size_t)row * VALUE_DIM);
    const float4* g4 = (const float4*)og;
    float acc = 0.f;
#pragma unroll
    for (int j = 0; j < 4; ++j) {                     // 1024/4/64 = 4
        float4 a = w4[lane + 64 * j];
        float4 b = g4[lane + 64 * j];
        acc += a.x * b.x + a.y * b.y + a.z * b.z + a.w * b.w;
    }
    acc = wave_reduce_sum(acc);
    if (lane == 0) y[row] = acc;
}

extern "C" void kernel_launch(void* const* d_in, const int* in_sizes, int n_in,
                              void* d_out, int out_size, void* d_ws, size_t ws_size,
                              hipStream_t stream) {
    const float* x     = (const float*)d_in[0];
    const float* Wqkv  = (const float*)d_in[1];
    const float* Wz    = (const float*)d_in[2];
    const float* Wa    = (const float*)d_in[3];
    const float* Wb    = (const float*)d_in[4];
    const float* Wout  = (const float*)d_in[5];
    const float* convw = (const float*)d_in[6];
    const float* Alog  = (const float*)d_in[7];
    const float* dtb   = (const float*)d_in[8];
    const float* normw = (const float*)d_in[9];
    const float* state = (const float*)d_in[10];
    const float* cch   = (const float*)d_in[11];

    float* ws = (float*)d_ws;              // [0,3104): qkv|z|a|b
    float* og = ws + NROWS1;               // [3104,4128): gated out (16B-aligned: 3104*4 % 16 == 0)
    float* y  = (float*)d_out;

    gemv_in<<<NROWS1 / 4, 256, 0, stream>>>(x, Wqkv, Wz, Wa, Wb, ws);
    decode_core<<<HV, 256, 0, stream>>>(ws, convw, cch, Alog, dtb, normw, state, og);
    gemv_out<<<H / 4, 256, 0, stream>>>(Wout, og, y);
}